// Round 5
// baseline (106.302 us; speedup 1.0000x reference)
//
#include <hip/hip_runtime.h>
#include <cstdint>
#include <cstddef>

#define NPTS   4096
#define BATCH  4
#define KNN    8
#define NC     16          // chunks (ranges) per cloud scan
#define CHN    (NPTS / NC) // 256 candidates per range
#define PD     4           // partial STORAGE depth per chunk (uint4)
#define EPS_F  1e-12f
#define NBLK2  ((BATCH * NPTS) / 64)   // 256 loss blocks
#define ROWU   16          // uints per prepped MFMA row (64 B = 32 bf16 K-slots)
#define ONE_BF 0x3F80u     // bf16(1.0)
#define BIAS_BF 0x3A80u    // bf16(2^-10): keeps self-d2 positive

typedef __attribute__((ext_vector_type(8))) short short8;  // 8 bf16 = 4 VGPR
typedef __attribute__((ext_vector_type(4))) float f32x4;

__device__ __forceinline__ uint32_t u32min(uint32_t a, uint32_t b) { return a < b ? a : b; }
__device__ __forceinline__ uint32_t u32max(uint32_t a, uint32_t b) { return a > b ? a : b; }

__device__ __forceinline__ uint32_t umed3(uint32_t a, uint32_t b, uint32_t c) {
  uint32_t d;
  asm("v_med3_u32 %0, %1, %2, %3" : "=v"(d) : "v"(a), "v"(b), "v"(c));
  return d;
}

// Insert key into ascending D-list, dropping the largest: 1 min + (D-1) med3.
template <int D>
__device__ __forceinline__ void insertD(uint32_t (&loc)[D], uint32_t key) {
  uint32_t prev = loc[0];
  loc[0] = u32min(prev, key);
#pragma unroll
  for (int m = 1; m < D; ++m) {
    const uint32_t cur = loc[m];
    loc[m] = umed3(prev, cur, key);
    prev = cur;
  }
}

// Two sorted-4 lists -> one fully sorted 8 (bitonic cleanup, 12 CEs).
__device__ __forceinline__ void merge44(const uint2 a0, const uint2 a1,
                                        const uint2 b0, const uint2 b1,
                                        uint32_t s[KNN]) {
  s[0] = a0.x; s[1] = a0.y; s[2] = a1.x; s[3] = a1.y;
  s[4] = b1.y; s[5] = b1.x; s[6] = b0.y; s[7] = b0.x;  // b reversed -> bitonic
#define CEU(x, y) { uint32_t lo = u32min(s[x], s[y]); uint32_t hi = u32max(s[x], s[y]); s[x] = lo; s[y] = hi; }
  CEU(0,4) CEU(1,5) CEU(2,6) CEU(3,7)
  CEU(0,2) CEU(1,3) CEU(4,6) CEU(5,7)
  CEU(0,1) CEU(2,3) CEU(4,5) CEU(6,7)
#undef CEU
}

// ---------------------------------------------------------------------------
// bf16 helpers (RN-even, pure bit math — no API dependence)
// ---------------------------------------------------------------------------
__device__ __forceinline__ uint32_t rnbf(float x) {
  const uint32_t u = __float_as_uint(x);
  return (u + 0x7FFFu + ((u >> 16) & 1u)) >> 16;
}
__device__ __forceinline__ float frombf(uint32_t h) { return __uint_as_float(h << 16); }

// ---------------------------------------------------------------------------
// Kernel 0: prep — per point, 2-limb bf16 split + 3-limb norm, packed into
// MFMA K-slot rows. A-row (candidate side) carries -2*limbs + norm limbs +
// bias; B-row (query side) carries limbs + norm limbs. K-slot pairing
// (A[k]*B[k]): k0-2 -2ch*qh | k3-5 -2ch*ql | k6-8 -2cl*qh | k9-11 -2cl*ql
// | k12,13 nc_h,nc_l*1 | k14,15 1*np_h,np_l | k16 nc_l2*1 | k17 1*np_l2
// | k18 bias*1 | k19-31 zero.  Sum = |c~-q~|^2 + 2^-10 (exact d2 of the
// bf16-rounded points, +-fp32-accum noise).
// ---------------------------------------------------------------------------
__global__ void __launch_bounds__(256)
prep_k(const float* __restrict__ pred, const float* __restrict__ tgt,
       uint32_t* __restrict__ arow, uint32_t* __restrict__ brow,
       uint32_t* __restrict__ ticket) {
  if (blockIdx.x == 0 && threadIdx.x == 0) *ticket = 0u;
  const int t = blockIdx.x * 256 + threadIdx.x;   // 0..32767
  const int cloud = t >> 14, b = (t >> 12) & 3, j = t & (NPTS - 1);
  const float* pts = (cloud ? tgt : pred) + (size_t)b * NPTS * 3;
  const float x = pts[3 * j], y = pts[3 * j + 1], z = pts[3 * j + 2];

  const uint32_t hx = rnbf(x); const float fx = frombf(hx);
  const uint32_t lx = rnbf(x - fx); const float gx = fx + frombf(lx);
  const uint32_t hy = rnbf(y); const float fy = frombf(hy);
  const uint32_t ly = rnbf(y - fy); const float gy = fy + frombf(ly);
  const uint32_t hz = rnbf(z); const float fz = frombf(hz);
  const uint32_t lz = rnbf(z - fz); const float gz = fz + frombf(lz);

  const float n = fmaf(gx, gx, fmaf(gy, gy, gz * gz));
  const uint32_t nh = rnbf(n);  const float r1 = n - frombf(nh);
  const uint32_t nl = rnbf(r1); const float r2 = r1 - frombf(nl);
  const uint32_t nl2 = rnbf(r2);

  const uint32_t mhx = rnbf(-2.f * fx), mhy = rnbf(-2.f * fy), mhz = rnbf(-2.f * fz);
  const uint32_t mlx = rnbf(-2.f * frombf(lx)), mly = rnbf(-2.f * frombf(ly)),
                 mlz = rnbf(-2.f * frombf(lz));

  uint32_t* ap = arow + ((size_t)(cloud * BATCH + b) * NPTS + j) * ROWU;
  uint32_t* bp = brow + ((size_t)(cloud * BATCH + b) * NPTS + j) * ROWU;

  // A row: [mhx mhy mhz mhx mhy mhz | mlx mly mlz mlx mly mlz | nh nl 1 1 | nl2 1 bias 0 | 0..]
  *(uint4*)(ap + 0) = make_uint4(mhx | (mhy << 16), mhz | (mhx << 16),
                                 mhy | (mhz << 16), mlx | (mly << 16));
  *(uint4*)(ap + 4) = make_uint4(mlz | (mlx << 16), mly | (mlz << 16),
                                 nh | (nl << 16), ONE_BF | (ONE_BF << 16));
  *(uint4*)(ap + 8) = make_uint4(nl2 | (ONE_BF << 16), BIAS_BF, 0u, 0u);
  *(uint4*)(ap + 12) = make_uint4(0u, 0u, 0u, 0u);

  // B row: [hx hy hz lx ly lz | hx hy hz lx ly lz | 1 1 nh nl | 1 nl2 1 0 | 0..]
  *(uint4*)(bp + 0) = make_uint4(hx | (hy << 16), hz | (lx << 16),
                                 ly | (lz << 16), hx | (hy << 16));
  *(uint4*)(bp + 4) = make_uint4(hz | (lx << 16), ly | (lz << 16),
                                 ONE_BF | (ONE_BF << 16), nh | (nl << 16));
  *(uint4*)(bp + 8) = make_uint4(ONE_BF | (nl2 << 16), ONE_BF, 0u, 0u);
  *(uint4*)(bp + 12) = make_uint4(0u, 0u, 0u, 0u);
}

// ---------------------------------------------------------------------------
// Kernel 1: MFMA kNN partials. Wave = 16 queries x 2048 candidates
// (8 ranges x 16 tiles of 16x16x32). C map (m89-verified): col=lane&15 =
// query, row=(lane>>4)*4+reg = candidate -> candidate axis is lane-local,
// selection per lane = depth-D insert over its 64 candidates/range. Range
// end: 4 lane-groups combine via LDS + merge44 -> exact top-4/range (self
// range: depth-4, drop rank 0 -> top-3, pad). Partial format == old scheme.
// ---------------------------------------------------------------------------
template <int D>
__device__ __forceinline__ void range_body(const uint32_t* __restrict__ abase,
                                           const short8 bf, int rangeAbs,
                                           int lane, uint32_t vjbase,
                                           uint32_t* __restrict__ outp,
                                           int strip, uint4* __restrict__ ldsrow) {
  uint32_t E[D];
#pragma unroll
  for (int k = 0; k < D; ++k) E[k] = 0xFFFFFFFFu;

  const uint32_t* ab = abase + ((size_t)rangeAbs * CHN + (lane & 15)) * ROWU + (lane >> 4) * 4;
  short8 afr[16];
#pragma unroll
  for (int t = 0; t < 16; ++t) afr[t] = *(const short8*)(ab + (size_t)t * 16 * ROWU);

  const f32x4 zacc = {0.f, 0.f, 0.f, 0.f};
#pragma unroll
  for (int t = 0; t < 16; ++t) {
    const f32x4 acc = __builtin_amdgcn_mfma_f32_16x16x32_bf16(afr[t], bf, zacc, 0, 0, 0);
    const uint32_t jt = (uint32_t)(rangeAbs * CHN + t * 16) + vjbase;
    insertD<D>(E, (__float_as_uint(acc[0]) & 0xFFFFF000u) | jt);
    insertD<D>(E, ((__float_as_uint(acc[1]) & 0xFFFFF000u) | jt) | 1u);
    insertD<D>(E, ((__float_as_uint(acc[2]) & 0xFFFFF000u) | jt) | 2u);
    insertD<D>(E, ((__float_as_uint(acc[3]) & 0xFFFFF000u) | jt) | 3u);
  }

  ldsrow[lane] = make_uint4(E[0], E[1], E[2], (D == 4) ? E[3] : 0xFFFFFFFFu);
  if (lane < 16) {
    const uint4 q0 = ldsrow[lane], q1 = ldsrow[lane + 16],
                q2 = ldsrow[lane + 32], q3 = ldsrow[lane + 48];
    uint32_t sa[KNN], sb[KNN], s[KNN];
    merge44(make_uint2(q0.x, q0.y), make_uint2(q0.z, q0.w),
            make_uint2(q1.x, q1.y), make_uint2(q1.z, q1.w), sa);
    merge44(make_uint2(q2.x, q2.y), make_uint2(q2.z, q2.w),
            make_uint2(q3.x, q3.y), make_uint2(q3.z, q3.w), sb);
    merge44(make_uint2(sa[0], sa[1]), make_uint2(sa[2], sa[3]),
            make_uint2(sb[0], sb[1]), make_uint2(sb[2], sb[3]), s);
    const uint4 o = (D == 4) ? make_uint4(s[1], s[2], s[3], 0xFFFFFFFFu)
                             : make_uint4(s[0], s[1], s[2], s[3]);
    uint32_t* p = outp + ((size_t)rangeAbs * NPTS + strip * 16 + lane) * PD;
    *(uint4*)p = o;
  }
}

__global__ void __launch_bounds__(256, 4)
knn_mfma_k(const uint32_t* __restrict__ arow, const uint32_t* __restrict__ brow,
           uint32_t* __restrict__ partial) {
  __shared__ uint4 ldsw[4][64];
  const int tid = threadIdx.x, lane = tid & 63, wid = tid >> 6;
  const int w = blockIdx.x * 4 + wid;          // 0..4095
  const int half = w & 1;
  const int strip = (w >> 1) & 255;
  const int b = (w >> 9) & 3;
  const int cloud = w >> 11;
  const int cb = cloud * BATCH + b;

  const uint32_t* abase = arow + (size_t)cb * NPTS * ROWU;
  const uint32_t* bbase = brow + (size_t)cb * NPTS * ROWU;
  const short8 bf = *(const short8*)(bbase + ((size_t)(strip * 16 + (lane & 15))) * ROWU
                                     + (lane >> 4) * 4);
  const uint32_t vjbase = (uint32_t)((lane >> 4) * 4);
  uint32_t* outp = partial + (size_t)cb * NC * NPTS * PD;
  const int selfRange = strip >> 4;

#pragma unroll 1
  for (int rr = 0; rr < 8; ++rr) {
    const int rangeAbs = half * 8 + rr;
    if (rangeAbs == selfRange)
      range_body<4>(abase, bf, rangeAbs, lane, vjbase, outp, strip, ldsw[wid]);
    else
      range_body<3>(abase, bf, rangeAbs, lane, vjbase, outp, strip, ldsw[wid]);
  }
}

// Merge two sorted-ascending 8-lists, keep the smallest 8, sorted.
__device__ __forceinline__ void merge2(uint32_t A[KNN], const uint32_t B[KNN]) {
  uint32_t t[KNN];
#pragma unroll
  for (int m = 0; m < KNN; ++m) t[m] = u32min(A[m], B[KNN - 1 - m]);
#define CEU(x, y) { uint32_t lo = u32min(t[x], t[y]); uint32_t hi = u32max(t[x], t[y]); t[x] = lo; t[y] = hi; }
  CEU(0,4) CEU(1,5) CEU(2,6) CEU(3,7)
  CEU(0,2) CEU(1,3) CEU(4,6) CEU(5,7)
  CEU(0,1) CEU(2,3) CEU(4,5) CEU(6,7)
#undef CEU
#pragma unroll
  for (int m = 0; m < KNN; ++m) A[m] = t[m];
}

// Merge all NC=16 sorted-4 lists for point i -> global top-8 (sorted).
__device__ __forceinline__ void merge_all(const uint32_t* __restrict__ base,
                                          int i, uint32_t v[KNN]) {
  const size_t stride = (size_t)NPTS * PD;
  const uint32_t* p = base + (size_t)i * PD;
  uint2 q[NC][2];
#pragma unroll
  for (int c = 0; c < NC; ++c) {
    q[c][0] = *(const uint2*)(p + (size_t)c * stride);
    q[c][1] = *(const uint2*)(p + (size_t)c * stride + 2);
  }
  uint32_t L[NC / 2][KNN];
#pragma unroll
  for (int c = 0; c < NC / 2; ++c)
    merge44(q[2 * c][0], q[2 * c][1], q[2 * c + 1][0], q[2 * c + 1][1], L[c]);
  merge2(L[0], L[1]); merge2(L[2], L[3]); merge2(L[4], L[5]); merge2(L[6], L[7]);
  merge2(L[0], L[2]); merge2(L[4], L[6]);
  merge2(L[0], L[4]);
#pragma unroll
  for (int m = 0; m < KNN; ++m) v[m] = L[0][m];
}

// Per-cloud: coord gather (8 independent loads), density/cov/unit vectors.
__device__ __forceinline__ void cloud_stats(const float* __restrict__ C, int i,
                                            const uint32_t v[KNN],
                                            float& dsum, float cov[6],
                                            float nx[KNN], float ny[KNN], float nz[KNN]) {
  const float qx = C[3 * i], qy = C[3 * i + 1], qz = C[3 * i + 2];
  float jx[KNN], jy[KNN], jz[KNN];
#pragma unroll
  for (int k = 0; k < KNN; ++k) {
    const int j = (int)(v[k] & 0xFFFu);
    jx[k] = C[3 * j]; jy[k] = C[3 * j + 1]; jz[k] = C[3 * j + 2];
  }
  dsum = 0.f;
#pragma unroll
  for (int m = 0; m < 6; ++m) cov[m] = 0.f;
#pragma unroll
  for (int k = 0; k < KNN; ++k) {
    const float ax = jx[k] - qx, ay = jy[k] - qy, az = jz[k] - qz;
    const float d2 = fmaf(ax, ax, fmaf(ay, ay, az * az));
    const float dist = sqrtf(fmaxf(d2, EPS_F));
    const float inv = 1.0f / fmaxf(dist, EPS_F);
    dsum += dist;
    cov[0] += ax * ax; cov[1] += ay * ay; cov[2] += az * az;
    cov[3] += ax * ay; cov[4] += ax * az; cov[5] += ay * az;
    nx[k] = ax * inv; ny[k] = ay * inv; nz[k] = az * inv;
  }
}

// ---------------------------------------------------------------------------
// Kernel 2 — proven verbatim: plain per-block stores + ticket finalize.
// ---------------------------------------------------------------------------
__global__ void __launch_bounds__(64, 1)
loss_k(const float* __restrict__ pred, const float* __restrict__ tgt,
       const uint32_t* __restrict__ partial, double* __restrict__ bsum,
       uint32_t* __restrict__ ticket, float* __restrict__ out) {
  const int p = blockIdx.x * 64 + threadIdx.x;   // 0 .. 16383
  const int b = p >> 12;
  const int i = p & (NPTS - 1);

  const float* __restrict__ P = pred + (size_t)b * NPTS * 3;
  const float* __restrict__ T = tgt  + (size_t)b * NPTS * 3;

  const size_t cstride = (size_t)NC * NPTS * PD;
  uint32_t vp[KNN], vt[KNN];
  merge_all(partial + (size_t)(0 * BATCH + b) * cstride, i, vp);
  merge_all(partial + (size_t)(1 * BATCH + b) * cstride, i, vt);

  float dsp, dst, pcov[6], tcov[6];
  float pnx[KNN], pny[KNN], pnz[KNN], tnx[KNN], tny[KNN], tnz[KNN];
  cloud_stats(P, i, vp, dsp, pcov, pnx, pny, pnz);
  cloud_stats(T, i, vt, dst, tcov, tnx, tny, tnz);

  float sdot = 0.f;
#pragma unroll
  for (int k = 0; k < KNN; ++k)
    sdot += pnx[k] * tnx[k] + pny[k] * tny[k] + pnz[k] * tnz[k];

  const float densp = dsp * (1.0f / KNN);
  const float denst = dst * (1.0f / KNN);
  float e = (densp - denst) * (densp - denst);

  const float dxx = (pcov[0] - tcov[0]) * (1.0f / KNN);
  const float dyy = (pcov[1] - tcov[1]) * (1.0f / KNN);
  const float dzz = (pcov[2] - tcov[2]) * (1.0f / KNN);
  const float dxy = (pcov[3] - tcov[3]) * (1.0f / KNN);
  const float dxz = (pcov[4] - tcov[4]) * (1.0f / KNN);
  const float dyz = (pcov[5] - tcov[5]) * (1.0f / KNN);
  float cfro = sqrtf(dxx * dxx + dyy * dyy + dzz * dzz
                     + 2.0f * (dxy * dxy + dxz * dxz + dyz * dyz));
  float s = sdot;

#pragma unroll
  for (int off = 32; off > 0; off >>= 1) {
    e    += __shfl_down(e, off);
    s    += __shfl_down(s, off);
    cfro += __shfl_down(cfro, off);
  }

  unsigned rank = 0u;
  if (threadIdx.x == 0) {
    double* d = bsum + 3 * (size_t)blockIdx.x;
    d[0] = (double)e; d[1] = (double)s; d[2] = (double)cfro;
    __threadfence();                       // release
    rank = atomicAdd(ticket, 1u) + 1u;
  }
  rank = __shfl(rank, 0);
  if (rank == (unsigned)NBLK2) {           // last block: whole wave reduces
    __threadfence();                       // acquire
    double ee = 0.0, ss = 0.0, cc = 0.0;
#pragma unroll
    for (int g = 0; g < NBLK2 / 64; ++g) {
      double* d = bsum + 3 * (size_t)(threadIdx.x + 64 * g);
      ee += __hip_atomic_load(&d[0], __ATOMIC_RELAXED, __HIP_MEMORY_SCOPE_AGENT);
      ss += __hip_atomic_load(&d[1], __ATOMIC_RELAXED, __HIP_MEMORY_SCOPE_AGENT);
      cc += __hip_atomic_load(&d[2], __ATOMIC_RELAXED, __HIP_MEMORY_SCOPE_AGENT);
    }
#pragma unroll
    for (int off = 32; off > 0; off >>= 1) {
      ee += __shfl_down(ee, off);
      ss += __shfl_down(ss, off);
      cc += __shfl_down(cc, off);
    }
    if (threadIdx.x == 0) {
      const double BN = (double)BATCH * (double)NPTS;
      out[0] = (float)(ee / BN + 0.5 * (1.0 - ss / (BN * (double)KNN)) + 0.5 * (cc / BN));
    }
  }
}

extern "C" void kernel_launch(void* const* d_in, const int* in_sizes, int n_in,
                              void* d_out, int out_size, void* d_ws, size_t ws_size,
                              hipStream_t stream) {
  const float* pred = (const float*)d_in[0];
  const float* tgt  = (const float*)d_in[1];
  uint32_t* ticket  = (uint32_t*)((char*)d_ws + 64);      // 1 u32
  double*   bsum    = (double*)((char*)d_ws + 4096);      // 256 x 3 doubles
  uint32_t* partial = (uint32_t*)((char*)d_ws + 65536);   // 8.4 MB
  uint32_t* arow    = (uint32_t*)((char*)d_ws + (16u << 20));  // 2 MB
  uint32_t* brow    = (uint32_t*)((char*)d_ws + (20u << 20));  // 2 MB

  prep_k<<<(2 * BATCH * NPTS) / 256, 256, 0, stream>>>(pred, tgt, arow, brow, ticket);
  knn_mfma_k<<<1024, 256, 0, stream>>>(arow, brow, partial);
  loss_k<<<NBLK2, 64, 0, stream>>>(pred, tgt, partial, bsum, ticket, (float*)d_out);
}

// Round 6
// 102.320 us; speedup vs baseline: 1.0389x; 1.0389x over previous
//
#include <hip/hip_runtime.h>
#include <cstdint>
#include <cstddef>

#define NPTS   4096
#define BATCH  4
#define KNN    8
#define NC     16          // chunks per cloud scan
#define CHN    (NPTS / NC) // 256 candidates per chunk
#define PD     4           // partial STORAGE depth per chunk (uint4; slot 3 = pad)
#define SD     3           // scan list depth (top-3/chunk)
#define EPS_F  1e-12f
#define NBLK2  ((BATCH * NPTS) / 64)   // 256 loss blocks

typedef __attribute__((ext_vector_type(2))) float f32x2;
typedef __attribute__((ext_vector_type(4))) float f32x4;

__device__ __forceinline__ uint32_t u32min(uint32_t a, uint32_t b) { return a < b ? a : b; }
__device__ __forceinline__ uint32_t u32max(uint32_t a, uint32_t b) { return a > b ? a : b; }

// v_med3_u32: for sorted a<=b, med3(a,b,x) == clamp(x,a,b) — one instruction.
__device__ __forceinline__ uint32_t umed3(uint32_t a, uint32_t b, uint32_t c) {
  uint32_t d;
  asm("v_med3_u32 %0, %1, %2, %3" : "=v"(d) : "v"(a), "v"(b), "v"(c));
  return d;
}

// Packed fp32 (VOP3P, CDNA2+): 2 candidates per instruction. IEEE f32 ops,
// bit-identical to the scalar chain they replace.
__device__ __forceinline__ f32x2 pk_sub(f32x2 a, f32x2 b) {  // a - b
  f32x2 d;
  asm("v_pk_add_f32 %0, %1, %2 neg_lo:[0,1] neg_hi:[0,1]" : "=v"(d) : "v"(a), "v"(b));
  return d;
}
__device__ __forceinline__ f32x2 pk_mul(f32x2 a, f32x2 b) {
  f32x2 d;
  asm("v_pk_mul_f32 %0, %1, %2" : "=v"(d) : "v"(a), "v"(b));
  return d;
}
__device__ __forceinline__ f32x2 pk_fma(f32x2 a, f32x2 b, f32x2 c) {  // a*b + c
  f32x2 d;
  asm("v_pk_fma_f32 %0, %1, %2, %3" : "=v"(d) : "v"(a), "v"(b), "v"(c));
  return d;
}
__device__ __forceinline__ f32x2 lo2(f32x4 v) { return __builtin_shufflevector(v, v, 0, 1); }
__device__ __forceinline__ f32x2 hi2(f32x4 v) { return __builtin_shufflevector(v, v, 2, 3); }

// Insert key into ascending D-list, dropping the largest: 1 min + (D-1) med3.
template <int D>
__device__ __forceinline__ void insertD(uint32_t (&loc)[D], uint32_t key) {
  uint32_t prev = loc[0];
  loc[0] = u32min(prev, key);
#pragma unroll
  for (int m = 1; m < D; ++m) {
    const uint32_t cur = loc[m];
    loc[m] = umed3(prev, cur, key);
    prev = cur;
  }
}

// Packed-f32 candidate scan over the SoA LDS chunk. Per 4 candidates:
// 3 uniform ds_read_b128 (broadcast) + 2x{3 pk_sub + pk_mul + 2 pk_fma}
// + 4x{and_or key-pack + insertD}. Distance op order (dz*dz -> +dy*dy ->
// +dx*dx, operands q-c) is IEEE-identical to the proven scalar chain ->
// bit-identical keys and selection.
template <int D>
__device__ __forceinline__ void scan_packed(const float* __restrict__ xs,
                                            const float* __restrict__ ys,
                                            const float* __restrict__ zs,
                                            int j0, f32x2 qx2, f32x2 qy2, f32x2 qz2,
                                            uint32_t (&loc)[D]) {
#pragma unroll
  for (int k = 0; k < D; ++k) loc[k] = 0xFFFFFFFFu;
#pragma unroll 2
  for (int t4 = 0; t4 < CHN / 4; ++t4) {
    const f32x4 xq = *(const f32x4*)&xs[4 * t4];
    const f32x4 yq = *(const f32x4*)&ys[4 * t4];
    const f32x4 zq = *(const f32x4*)&zs[4 * t4];
    const uint32_t jb = (uint32_t)(j0 + 4 * t4);
    {
      const f32x2 dx = pk_sub(qx2, lo2(xq));
      const f32x2 dy = pk_sub(qy2, lo2(yq));
      const f32x2 dz = pk_sub(qz2, lo2(zq));
      f32x2 t = pk_mul(dz, dz);
      t = pk_fma(dy, dy, t);
      t = pk_fma(dx, dx, t);
      insertD<D>(loc, (__float_as_uint(t[0]) & 0xFFFFF000u) | (jb + 0u));
      insertD<D>(loc, (__float_as_uint(t[1]) & 0xFFFFF000u) | (jb + 1u));
    }
    {
      const f32x2 dx = pk_sub(qx2, hi2(xq));
      const f32x2 dy = pk_sub(qy2, hi2(yq));
      const f32x2 dz = pk_sub(qz2, hi2(zq));
      f32x2 t = pk_mul(dz, dz);
      t = pk_fma(dy, dy, t);
      t = pk_fma(dx, dx, t);
      insertD<D>(loc, (__float_as_uint(t[0]) & 0xFFFFF000u) | (jb + 2u));
      insertD<D>(loc, (__float_as_uint(t[1]) & 0xFFFFF000u) | (jb + 3u));
    }
  }
}

// ---------------------------------------------------------------------------
// Kernel 1: per-(cloud,batch,point,chunk) top-3 by truncated key (top-4 with
// rank-0 self-drop for the self chunk — block-uniform branch). Key =
// (float_bits(d2) & 0xFFFFF000) | j; ties -> ascending j (lax.top_k).
// R1 structure; change: SoA LDS staging (xs/ys/zs) + packed-fp32 distance
// (v_pk_*, 2 candidates/instr) — distance VALU halves, selection unchanged,
// results bit-identical to R1/R4.
// ---------------------------------------------------------------------------
__global__ void __launch_bounds__(256, 8)
knn_partial_k(const float* __restrict__ pred, const float* __restrict__ tgt,
              uint32_t* __restrict__ partial, uint32_t* __restrict__ ticket) {
  if (blockIdx.x == 0 && threadIdx.x == 0) *ticket = 0u;

  __shared__ __align__(16) float xs[CHN];
  __shared__ __align__(16) float ys[CHN];
  __shared__ __align__(16) float zs[CHN];

  int bx = blockIdx.x;
  const int chunk = bx & (NC - 1); bx /= NC;
  const int ig    = bx & 15; bx >>= 4;
  const int b     = bx & 3;  bx >>= 2;
  const int cloud = bx;  // 0 = pred, 1 = target

  const float* __restrict__ pts = (cloud ? tgt : pred) + (size_t)b * NPTS * 3;
  const int tid = threadIdx.x;
  const int i = ig * 256 + tid;
  const int j0 = chunk * CHN;

  // Stage this chunk into SoA LDS (one point per thread; packed-pair friendly).
  {
    const int j = j0 + tid;
    xs[tid] = pts[3 * j + 0];
    ys[tid] = pts[3 * j + 1];
    zs[tid] = pts[3 * j + 2];
  }
  const float xix = pts[3 * i + 0];
  const float xiy = pts[3 * i + 1];
  const float xiz = pts[3 * i + 2];
  __syncthreads();

  const f32x2 qx2 = {xix, xix};
  const f32x2 qy2 = {xiy, xiy};
  const f32x2 qz2 = {xiz, xiz};

  uint4 o;
  if (ig == chunk) {           // self chunk (CHN == 256): depth 4, drop rank 0
    uint32_t loc[SD + 1];
    scan_packed<SD + 1>(xs, ys, zs, j0, qx2, qy2, qz2, loc);
    o = make_uint4(loc[1], loc[2], loc[3], 0xFFFFFFFFu);
  } else {
    uint32_t loc[SD];
    scan_packed<SD>(xs, ys, zs, j0, qx2, qy2, qz2, loc);
    o = make_uint4(loc[0], loc[1], loc[2], 0xFFFFFFFFu);
  }
  uint32_t* p = partial +
      ((((size_t)(cloud * BATCH + b) * NC + chunk) * NPTS) + (size_t)i) * PD;
  *(uint4*)p = o;
}

// Merge two sorted-ascending 8-lists, keep the smallest 8, sorted.
__device__ __forceinline__ void merge2(uint32_t A[KNN], const uint32_t B[KNN]) {
  uint32_t t[KNN];
#pragma unroll
  for (int m = 0; m < KNN; ++m) t[m] = u32min(A[m], B[KNN - 1 - m]);
#define CEU(x, y) { uint32_t lo = u32min(t[x], t[y]); uint32_t hi = u32max(t[x], t[y]); t[x] = lo; t[y] = hi; }
  CEU(0,4) CEU(1,5) CEU(2,6) CEU(3,7)
  CEU(0,2) CEU(1,3) CEU(4,6) CEU(5,7)
  CEU(0,1) CEU(2,3) CEU(4,5) CEU(6,7)
#undef CEU
#pragma unroll
  for (int m = 0; m < KNN; ++m) A[m] = t[m];
}

// Two sorted-4 lists -> one fully sorted 8 (bitonic cleanup, 12 CEs).
// Pad entries (0xFFFFFFFF) sort to the top and never reach the final top-8
// (16 chunks x 3 real keys = 48 >= 8 real candidates).
__device__ __forceinline__ void merge44(const uint2 a0, const uint2 a1,
                                        const uint2 b0, const uint2 b1,
                                        uint32_t s[KNN]) {
  s[0] = a0.x; s[1] = a0.y; s[2] = a1.x; s[3] = a1.y;
  s[4] = b1.y; s[5] = b1.x; s[6] = b0.y; s[7] = b0.x;  // b reversed -> bitonic
#define CEU(x, y) { uint32_t lo = u32min(s[x], s[y]); uint32_t hi = u32max(s[x], s[y]); s[x] = lo; s[y] = hi; }
  CEU(0,4) CEU(1,5) CEU(2,6) CEU(3,7)
  CEU(0,2) CEU(1,3) CEU(4,6) CEU(5,7)
  CEU(0,1) CEU(2,3) CEU(4,5) CEU(6,7)
#undef CEU
}

// Merge all NC=16 sorted-4 lists for point i -> global top-8 (sorted).
__device__ __forceinline__ void merge_all(const uint32_t* __restrict__ base,
                                          int i, uint32_t v[KNN]) {
  const size_t stride = (size_t)NPTS * PD;
  const uint32_t* p = base + (size_t)i * PD;
  uint2 q[NC][2];
#pragma unroll
  for (int c = 0; c < NC; ++c) {
    q[c][0] = *(const uint2*)(p + (size_t)c * stride);
    q[c][1] = *(const uint2*)(p + (size_t)c * stride + 2);
  }
  uint32_t L[NC / 2][KNN];
#pragma unroll
  for (int c = 0; c < NC / 2; ++c)
    merge44(q[2 * c][0], q[2 * c][1], q[2 * c + 1][0], q[2 * c + 1][1], L[c]);
  merge2(L[0], L[1]); merge2(L[2], L[3]); merge2(L[4], L[5]); merge2(L[6], L[7]);
  merge2(L[0], L[2]); merge2(L[4], L[6]);
  merge2(L[0], L[4]);
#pragma unroll
  for (int m = 0; m < KNN; ++m) v[m] = L[0][m];
}

// Per-cloud: coord gather (8 independent loads), density/cov/unit vectors.
__device__ __forceinline__ void cloud_stats(const float* __restrict__ C, int i,
                                            const uint32_t v[KNN],
                                            float& dsum, float cov[6],
                                            float nx[KNN], float ny[KNN], float nz[KNN]) {
  const float qx = C[3 * i], qy = C[3 * i + 1], qz = C[3 * i + 2];
  float jx[KNN], jy[KNN], jz[KNN];
#pragma unroll
  for (int k = 0; k < KNN; ++k) {
    const int j = (int)(v[k] & 0xFFFu);
    jx[k] = C[3 * j]; jy[k] = C[3 * j + 1]; jz[k] = C[3 * j + 2];
  }
  dsum = 0.f;
#pragma unroll
  for (int m = 0; m < 6; ++m) cov[m] = 0.f;
#pragma unroll
  for (int k = 0; k < KNN; ++k) {
    const float ax = jx[k] - qx, ay = jy[k] - qy, az = jz[k] - qz;
    const float d2 = fmaf(ax, ax, fmaf(ay, ay, az * az));
    const float dist = sqrtf(fmaxf(d2, EPS_F));
    const float inv = 1.0f / fmaxf(dist, EPS_F);
    dsum += dist;
    cov[0] += ax * ax; cov[1] += ay * ay; cov[2] += az * az;
    cov[3] += ax * ay; cov[4] += ax * az; cov[5] += ay * az;
    nx[k] = ax * inv; ny[k] = ay * inv; nz[k] = az * inv;
  }
}

// ---------------------------------------------------------------------------
// Kernel 2 — proven verbatim: plain per-block stores + ticket finalize.
// ---------------------------------------------------------------------------
__global__ void __launch_bounds__(64, 1)
loss_k(const float* __restrict__ pred, const float* __restrict__ tgt,
       const uint32_t* __restrict__ partial, double* __restrict__ bsum,
       uint32_t* __restrict__ ticket, float* __restrict__ out) {
  const int p = blockIdx.x * 64 + threadIdx.x;   // 0 .. 16383
  const int b = p >> 12;
  const int i = p & (NPTS - 1);

  const float* __restrict__ P = pred + (size_t)b * NPTS * 3;
  const float* __restrict__ T = tgt  + (size_t)b * NPTS * 3;

  const size_t cstride = (size_t)NC * NPTS * PD;
  uint32_t vp[KNN], vt[KNN];
  merge_all(partial + (size_t)(0 * BATCH + b) * cstride, i, vp);
  merge_all(partial + (size_t)(1 * BATCH + b) * cstride, i, vt);

  float dsp, dst, pcov[6], tcov[6];
  float pnx[KNN], pny[KNN], pnz[KNN], tnx[KNN], tny[KNN], tnz[KNN];
  cloud_stats(P, i, vp, dsp, pcov, pnx, pny, pnz);
  cloud_stats(T, i, vt, dst, tcov, tnx, tny, tnz);

  float sdot = 0.f;
#pragma unroll
  for (int k = 0; k < KNN; ++k)
    sdot += pnx[k] * tnx[k] + pny[k] * tny[k] + pnz[k] * tnz[k];

  const float densp = dsp * (1.0f / KNN);
  const float denst = dst * (1.0f / KNN);
  float e = (densp - denst) * (densp - denst);

  const float dxx = (pcov[0] - tcov[0]) * (1.0f / KNN);
  const float dyy = (pcov[1] - tcov[1]) * (1.0f / KNN);
  const float dzz = (pcov[2] - tcov[2]) * (1.0f / KNN);
  const float dxy = (pcov[3] - tcov[3]) * (1.0f / KNN);
  const float dxz = (pcov[4] - tcov[4]) * (1.0f / KNN);
  const float dyz = (pcov[5] - tcov[5]) * (1.0f / KNN);
  float cfro = sqrtf(dxx * dxx + dyy * dyy + dzz * dzz
                     + 2.0f * (dxy * dxy + dxz * dxz + dyz * dyz));
  float s = sdot;

#pragma unroll
  for (int off = 32; off > 0; off >>= 1) {
    e    += __shfl_down(e, off);
    s    += __shfl_down(s, off);
    cfro += __shfl_down(cfro, off);
  }

  unsigned rank = 0u;
  if (threadIdx.x == 0) {
    double* d = bsum + 3 * (size_t)blockIdx.x;
    d[0] = (double)e; d[1] = (double)s; d[2] = (double)cfro;
    __threadfence();                       // release: stores visible device-wide
    rank = atomicAdd(ticket, 1u) + 1u;
  }
  rank = __shfl(rank, 0);
  if (rank == (unsigned)NBLK2) {           // last block: whole wave reduces
    __threadfence();                       // acquire
    double ee = 0.0, ss = 0.0, cc = 0.0;
#pragma unroll
    for (int g = 0; g < NBLK2 / 64; ++g) {
      double* d = bsum + 3 * (size_t)(threadIdx.x + 64 * g);
      ee += __hip_atomic_load(&d[0], __ATOMIC_RELAXED, __HIP_MEMORY_SCOPE_AGENT);
      ss += __hip_atomic_load(&d[1], __ATOMIC_RELAXED, __HIP_MEMORY_SCOPE_AGENT);
      cc += __hip_atomic_load(&d[2], __ATOMIC_RELAXED, __HIP_MEMORY_SCOPE_AGENT);
    }
#pragma unroll
    for (int off = 32; off > 0; off >>= 1) {
      ee += __shfl_down(ee, off);
      ss += __shfl_down(ss, off);
      cc += __shfl_down(cc, off);
    }
    if (threadIdx.x == 0) {
      const double BN = (double)BATCH * (double)NPTS;
      out[0] = (float)(ee / BN + 0.5 * (1.0 - ss / (BN * (double)KNN)) + 0.5 * (cc / BN));
    }
  }
}

extern "C" void kernel_launch(void* const* d_in, const int* in_sizes, int n_in,
                              void* d_out, int out_size, void* d_ws, size_t ws_size,
                              hipStream_t stream) {
  const float* pred = (const float*)d_in[0];
  const float* tgt  = (const float*)d_in[1];
  uint32_t* ticket  = (uint32_t*)((char*)d_ws + 64);     // 1 u32
  double*   bsum    = (double*)((char*)d_ws + 4096);     // 256 x 3 doubles (6 KB)
  uint32_t* partial = (uint32_t*)((char*)d_ws + 65536);  // 8.4 MB

  knn_partial_k<<<2 * BATCH * (NPTS / 256) * NC, 256, 0, stream>>>(
      pred, tgt, partial, ticket);
  loss_k<<<NBLK2, 64, 0, stream>>>(
      pred, tgt, partial, bsum, ticket, (float*)d_out);
}

// Round 7
// 101.000 us; speedup vs baseline: 1.0525x; 1.0131x over previous
//
#include <hip/hip_runtime.h>
#include <cstdint>
#include <cstddef>

#define NPTS   4096
#define BATCH  4
#define KNN    8
#define NC     16          // chunks per cloud scan
#define CHN    (NPTS / NC) // 256 candidates per chunk
#define PD     4           // partial STORAGE depth per chunk (uint4; slot 3 = pad)
#define SD     3           // scan list depth (top-3/chunk)
#define EPS_F  1e-12f
#define NBLK2  ((BATCH * NPTS) / 64)   // 256 loss blocks

__device__ __forceinline__ uint32_t u32min(uint32_t a, uint32_t b) { return a < b ? a : b; }
__device__ __forceinline__ uint32_t u32max(uint32_t a, uint32_t b) { return a > b ? a : b; }

// v_med3_u32: for sorted a<=b, med3(a,b,x) == clamp(x,a,b) — one instruction.
__device__ __forceinline__ uint32_t umed3(uint32_t a, uint32_t b, uint32_t c) {
  uint32_t d;
  asm("v_med3_u32 %0, %1, %2, %3" : "=v"(d) : "v"(a), "v"(b), "v"(c));
  return d;
}

// Packed f16 (VOP3P): 2 f16 lanes per instruction at FULL rate (CDNA f16
// vector = 2x f32 rate) — unlike v_pk_*_f32 which is a 2-pass op (R6 null).
__device__ __forceinline__ uint32_t pk_add_h(uint32_t a, uint32_t b) {
  uint32_t d;
  asm("v_pk_add_f16 %0, %1, %2" : "=v"(d) : "v"(a), "v"(b));
  return d;
}
__device__ __forceinline__ uint32_t pk_mul_h(uint32_t a, uint32_t b) {
  uint32_t d;
  asm("v_pk_mul_f16 %0, %1, %2" : "=v"(d) : "v"(a), "v"(b));
  return d;
}
__device__ __forceinline__ uint32_t pk_fma_h(uint32_t a, uint32_t b, uint32_t c) {
  uint32_t d;
  asm("v_pk_fma_f16 %0, %1, %2, %3" : "=v"(d) : "v"(a), "v"(b), "v"(c));
  return d;
}

// Insert key into ascending D-list, dropping the largest: 1 min + (D-1) med3.
template <int D>
__device__ __forceinline__ void insertD(uint32_t (&loc)[D], uint32_t key) {
  uint32_t prev = loc[0];
  loc[0] = u32min(prev, key);
#pragma unroll
  for (int m = 1; m < D; ++m) {
    const uint32_t cur = loc[m];
    loc[m] = umed3(prev, cur, key);
    prev = cur;
  }
}

// f16-packed candidate scan over SoA f16 LDS arrays. Per 8 candidates:
// 3 uniform ds_read_b128 + 4x{3 pk_add + pk_mul + 2 pk_fma + 2 key + 2x insert}.
// Key = (f16_d2_bits << 16) | j : f16 bit pattern is monotone for d2 >= 0,
// j (<4096) fits the low 16 bits, ties resolve to ascending j (lax.top_k).
// Self-distance: query and candidate use the IDENTICAL (_Float16) conversion,
// so c + (-q) == 0 exactly -> self ranks 0 -> rank-0 drop stays sound.
template <int D>
__device__ __forceinline__ void scan_f16(const _Float16* __restrict__ xh,
                                         const _Float16* __restrict__ yh,
                                         const _Float16* __restrict__ zh,
                                         int j0, uint32_t nqx, uint32_t nqy, uint32_t nqz,
                                         uint32_t (&loc)[D]) {
#pragma unroll
  for (int k = 0; k < D; ++k) loc[k] = 0xFFFFFFFFu;
#pragma unroll 2
  for (int t8 = 0; t8 < CHN / 8; ++t8) {
    const uint4 xv = *(const uint4*)&xh[8 * t8];
    const uint4 yv = *(const uint4*)&yh[8 * t8];
    const uint4 zv = *(const uint4*)&zh[8 * t8];
    const uint32_t jb = (uint32_t)(j0 + 8 * t8);
#pragma unroll
    for (int p = 0; p < 4; ++p) {
      const uint32_t cx = (p == 0) ? xv.x : (p == 1) ? xv.y : (p == 2) ? xv.z : xv.w;
      const uint32_t cy = (p == 0) ? yv.x : (p == 1) ? yv.y : (p == 2) ? yv.z : yv.w;
      const uint32_t cz = (p == 0) ? zv.x : (p == 1) ? zv.y : (p == 2) ? zv.z : zv.w;
      const uint32_t dx = pk_add_h(cx, nqx);   // c - q (query pre-negated)
      const uint32_t dy = pk_add_h(cy, nqy);
      const uint32_t dz = pk_add_h(cz, nqz);
      uint32_t d2 = pk_mul_h(dz, dz);
      d2 = pk_fma_h(dy, dy, d2);
      d2 = pk_fma_h(dx, dx, d2);
      const uint32_t je = jb + 2u * (uint32_t)p;
      insertD<D>(loc, (d2 << 16) | je);              // low half -> cand 2p
      insertD<D>(loc, (d2 & 0xFFFF0000u) | (je + 1u)); // high half -> cand 2p+1
    }
  }
}

// ---------------------------------------------------------------------------
// Kernel 1: per-(cloud,batch,point,chunk) top-3 by f16 key (top-4 with
// rank-0 self-drop for the self chunk — block-uniform branch).
// R1/R6 structure (proven); change: f16 SoA LDS staging + packed-f16
// distance — TRUE 2x VALU-cycle rate (pk_f32 was 2-pass, R6 null). Key
// granularity (f16, 2^-11 rel) ~= the old 20-bit truncated-f32 key.
// ---------------------------------------------------------------------------
__global__ void __launch_bounds__(256, 8)
knn_partial_k(const float* __restrict__ pred, const float* __restrict__ tgt,
              uint32_t* __restrict__ partial, uint32_t* __restrict__ ticket) {
  if (blockIdx.x == 0 && threadIdx.x == 0) *ticket = 0u;

  __shared__ __align__(16) _Float16 xh[CHN];
  __shared__ __align__(16) _Float16 yh[CHN];
  __shared__ __align__(16) _Float16 zh[CHN];

  int bx = blockIdx.x;
  const int chunk = bx & (NC - 1); bx /= NC;
  const int ig    = bx & 15; bx >>= 4;
  const int b     = bx & 3;  bx >>= 2;
  const int cloud = bx;  // 0 = pred, 1 = target

  const float* __restrict__ pts = (cloud ? tgt : pred) + (size_t)b * NPTS * 3;
  const int tid = threadIdx.x;
  const int i = ig * 256 + tid;
  const int j0 = chunk * CHN;

  // Stage this chunk into f16 SoA LDS (one point per thread).
  {
    const int j = j0 + tid;
    xh[tid] = (_Float16)pts[3 * j + 0];
    yh[tid] = (_Float16)pts[3 * j + 1];
    zh[tid] = (_Float16)pts[3 * j + 2];
  }
  const float xix = pts[3 * i + 0];
  const float xiy = pts[3 * i + 1];
  const float xiz = pts[3 * i + 2];
  __syncthreads();

  // Pre-negated packed query halves ({-q,-q}) -> plain pk_add in the loop.
  union HU { _Float16 h[2]; uint32_t u; };
  HU ux, uy, uz;
  ux.h[0] = ux.h[1] = -(_Float16)xix;
  uy.h[0] = uy.h[1] = -(_Float16)xiy;
  uz.h[0] = uz.h[1] = -(_Float16)xiz;

  uint4 o;
  if (ig == chunk) {           // self chunk (CHN == 256): depth 4, drop rank 0
    uint32_t loc[SD + 1];
    scan_f16<SD + 1>(xh, yh, zh, j0, ux.u, uy.u, uz.u, loc);
    o = make_uint4(loc[1], loc[2], loc[3], 0xFFFFFFFFu);
  } else {
    uint32_t loc[SD];
    scan_f16<SD>(xh, yh, zh, j0, ux.u, uy.u, uz.u, loc);
    o = make_uint4(loc[0], loc[1], loc[2], 0xFFFFFFFFu);
  }
  uint32_t* p = partial +
      ((((size_t)(cloud * BATCH + b) * NC + chunk) * NPTS) + (size_t)i) * PD;
  *(uint4*)p = o;
}

// Merge two sorted-ascending 8-lists, keep the smallest 8, sorted.
__device__ __forceinline__ void merge2(uint32_t A[KNN], const uint32_t B[KNN]) {
  uint32_t t[KNN];
#pragma unroll
  for (int m = 0; m < KNN; ++m) t[m] = u32min(A[m], B[KNN - 1 - m]);
#define CEU(x, y) { uint32_t lo = u32min(t[x], t[y]); uint32_t hi = u32max(t[x], t[y]); t[x] = lo; t[y] = hi; }
  CEU(0,4) CEU(1,5) CEU(2,6) CEU(3,7)
  CEU(0,2) CEU(1,3) CEU(4,6) CEU(5,7)
  CEU(0,1) CEU(2,3) CEU(4,5) CEU(6,7)
#undef CEU
#pragma unroll
  for (int m = 0; m < KNN; ++m) A[m] = t[m];
}

// Two sorted-4 lists -> one fully sorted 8 (bitonic cleanup, 12 CEs).
// Pad entries (0xFFFFFFFF) sort to the top and never reach the final top-8
// (16 chunks x 3 real keys = 48 >= 8 real candidates).
__device__ __forceinline__ void merge44(const uint2 a0, const uint2 a1,
                                        const uint2 b0, const uint2 b1,
                                        uint32_t s[KNN]) {
  s[0] = a0.x; s[1] = a0.y; s[2] = a1.x; s[3] = a1.y;
  s[4] = b1.y; s[5] = b1.x; s[6] = b0.y; s[7] = b0.x;  // b reversed -> bitonic
#define CEU(x, y) { uint32_t lo = u32min(s[x], s[y]); uint32_t hi = u32max(s[x], s[y]); s[x] = lo; s[y] = hi; }
  CEU(0,4) CEU(1,5) CEU(2,6) CEU(3,7)
  CEU(0,2) CEU(1,3) CEU(4,6) CEU(5,7)
  CEU(0,1) CEU(2,3) CEU(4,5) CEU(6,7)
#undef CEU
}

// Merge all NC=16 sorted-4 lists for point i -> global top-8 (sorted).
__device__ __forceinline__ void merge_all(const uint32_t* __restrict__ base,
                                          int i, uint32_t v[KNN]) {
  const size_t stride = (size_t)NPTS * PD;
  const uint32_t* p = base + (size_t)i * PD;
  uint2 q[NC][2];
#pragma unroll
  for (int c = 0; c < NC; ++c) {
    q[c][0] = *(const uint2*)(p + (size_t)c * stride);
    q[c][1] = *(const uint2*)(p + (size_t)c * stride + 2);
  }
  uint32_t L[NC / 2][KNN];
#pragma unroll
  for (int c = 0; c < NC / 2; ++c)
    merge44(q[2 * c][0], q[2 * c][1], q[2 * c + 1][0], q[2 * c + 1][1], L[c]);
  merge2(L[0], L[1]); merge2(L[2], L[3]); merge2(L[4], L[5]); merge2(L[6], L[7]);
  merge2(L[0], L[2]); merge2(L[4], L[6]);
  merge2(L[0], L[4]);
#pragma unroll
  for (int m = 0; m < KNN; ++m) v[m] = L[0][m];
}

// Per-cloud: coord gather (8 independent loads), density/cov/unit vectors.
// Indices live in the low 16 bits of the key now (j < 4096 -> mask 0xFFF ok).
__device__ __forceinline__ void cloud_stats(const float* __restrict__ C, int i,
                                            const uint32_t v[KNN],
                                            float& dsum, float cov[6],
                                            float nx[KNN], float ny[KNN], float nz[KNN]) {
  const float qx = C[3 * i], qy = C[3 * i + 1], qz = C[3 * i + 2];
  float jx[KNN], jy[KNN], jz[KNN];
#pragma unroll
  for (int k = 0; k < KNN; ++k) {
    const int j = (int)(v[k] & 0xFFFu);
    jx[k] = C[3 * j]; jy[k] = C[3 * j + 1]; jz[k] = C[3 * j + 2];
  }
  dsum = 0.f;
#pragma unroll
  for (int m = 0; m < 6; ++m) cov[m] = 0.f;
#pragma unroll
  for (int k = 0; k < KNN; ++k) {
    const float ax = jx[k] - qx, ay = jy[k] - qy, az = jz[k] - qz;
    const float d2 = fmaf(ax, ax, fmaf(ay, ay, az * az));
    const float dist = sqrtf(fmaxf(d2, EPS_F));
    const float inv = 1.0f / fmaxf(dist, EPS_F);
    dsum += dist;
    cov[0] += ax * ax; cov[1] += ay * ay; cov[2] += az * az;
    cov[3] += ax * ay; cov[4] += ax * az; cov[5] += ay * az;
    nx[k] = ax * inv; ny[k] = ay * inv; nz[k] = az * inv;
  }
}

// ---------------------------------------------------------------------------
// Kernel 2 — proven verbatim: plain per-block stores + ticket finalize.
// ---------------------------------------------------------------------------
__global__ void __launch_bounds__(64, 1)
loss_k(const float* __restrict__ pred, const float* __restrict__ tgt,
       const uint32_t* __restrict__ partial, double* __restrict__ bsum,
       uint32_t* __restrict__ ticket, float* __restrict__ out) {
  const int p = blockIdx.x * 64 + threadIdx.x;   // 0 .. 16383
  const int b = p >> 12;
  const int i = p & (NPTS - 1);

  const float* __restrict__ P = pred + (size_t)b * NPTS * 3;
  const float* __restrict__ T = tgt  + (size_t)b * NPTS * 3;

  const size_t cstride = (size_t)NC * NPTS * PD;
  uint32_t vp[KNN], vt[KNN];
  merge_all(partial + (size_t)(0 * BATCH + b) * cstride, i, vp);
  merge_all(partial + (size_t)(1 * BATCH + b) * cstride, i, vt);

  float dsp, dst, pcov[6], tcov[6];
  float pnx[KNN], pny[KNN], pnz[KNN], tnx[KNN], tny[KNN], tnz[KNN];
  cloud_stats(P, i, vp, dsp, pcov, pnx, pny, pnz);
  cloud_stats(T, i, vt, dst, tcov, tnx, tny, tnz);

  float sdot = 0.f;
#pragma unroll
  for (int k = 0; k < KNN; ++k)
    sdot += pnx[k] * tnx[k] + pny[k] * tny[k] + pnz[k] * tnz[k];

  const float densp = dsp * (1.0f / KNN);
  const float denst = dst * (1.0f / KNN);
  float e = (densp - denst) * (densp - denst);

  const float dxx = (pcov[0] - tcov[0]) * (1.0f / KNN);
  const float dyy = (pcov[1] - tcov[1]) * (1.0f / KNN);
  const float dzz = (pcov[2] - tcov[2]) * (1.0f / KNN);
  const float dxy = (pcov[3] - tcov[3]) * (1.0f / KNN);
  const float dxz = (pcov[4] - tcov[4]) * (1.0f / KNN);
  const float dyz = (pcov[5] - tcov[5]) * (1.0f / KNN);
  float cfro = sqrtf(dxx * dxx + dyy * dyy + dzz * dzz
                     + 2.0f * (dxy * dxy + dxz * dxz + dyz * dyz));
  float s = sdot;

#pragma unroll
  for (int off = 32; off > 0; off >>= 1) {
    e    += __shfl_down(e, off);
    s    += __shfl_down(s, off);
    cfro += __shfl_down(cfro, off);
  }

  unsigned rank = 0u;
  if (threadIdx.x == 0) {
    double* d = bsum + 3 * (size_t)blockIdx.x;
    d[0] = (double)e; d[1] = (double)s; d[2] = (double)cfro;
    __threadfence();                       // release: stores visible device-wide
    rank = atomicAdd(ticket, 1u) + 1u;
  }
  rank = __shfl(rank, 0);
  if (rank == (unsigned)NBLK2) {           // last block: whole wave reduces
    __threadfence();                       // acquire
    double ee = 0.0, ss = 0.0, cc = 0.0;
#pragma unroll
    for (int g = 0; g < NBLK2 / 64; ++g) {
      double* d = bsum + 3 * (size_t)(threadIdx.x + 64 * g);
      ee += __hip_atomic_load(&d[0], __ATOMIC_RELAXED, __HIP_MEMORY_SCOPE_AGENT);
      ss += __hip_atomic_load(&d[1], __ATOMIC_RELAXED, __HIP_MEMORY_SCOPE_AGENT);
      cc += __hip_atomic_load(&d[2], __ATOMIC_RELAXED, __HIP_MEMORY_SCOPE_AGENT);
    }
#pragma unroll
    for (int off = 32; off > 0; off >>= 1) {
      ee += __shfl_down(ee, off);
      ss += __shfl_down(ss, off);
      cc += __shfl_down(cc, off);
    }
    if (threadIdx.x == 0) {
      const double BN = (double)BATCH * (double)NPTS;
      out[0] = (float)(ee / BN + 0.5 * (1.0 - ss / (BN * (double)KNN)) + 0.5 * (cc / BN));
    }
  }
}

extern "C" void kernel_launch(void* const* d_in, const int* in_sizes, int n_in,
                              void* d_out, int out_size, void* d_ws, size_t ws_size,
                              hipStream_t stream) {
  const float* pred = (const float*)d_in[0];
  const float* tgt  = (const float*)d_in[1];
  uint32_t* ticket  = (uint32_t*)((char*)d_ws + 64);     // 1 u32
  double*   bsum    = (double*)((char*)d_ws + 4096);     // 256 x 3 doubles (6 KB)
  uint32_t* partial = (uint32_t*)((char*)d_ws + 65536);  // 8.4 MB

  knn_partial_k<<<2 * BATCH * (NPTS / 256) * NC, 256, 0, stream>>>(
      pred, tgt, partial, ticket);
  loss_k<<<NBLK2, 64, 0, stream>>>(
      pred, tgt, partial, bsum, ticket, (float*)d_out);
}

// Round 8
// 99.745 us; speedup vs baseline: 1.0657x; 1.0126x over previous
//
#include <hip/hip_runtime.h>
#include <cstdint>
#include <cstddef>

#define NPTS   4096
#define BATCH  4
#define KNN    8
#define NC     16          // chunks per cloud scan
#define CHN    (NPTS / NC) // 256 candidates per chunk
#define PD     4           // partial STORAGE depth per chunk (uint4; slot 3 = pad)
#define SD     3           // scan list depth (top-3/chunk)
#define EPS_F  1e-12f
#define NBLK2  ((BATCH * NPTS) / 64)   // 256 loss blocks

__device__ __forceinline__ uint32_t u32min(uint32_t a, uint32_t b) { return a < b ? a : b; }
__device__ __forceinline__ uint32_t u32max(uint32_t a, uint32_t b) { return a > b ? a : b; }

// v_med3_u32: for sorted a<=b, med3(a,b,x) == clamp(x,a,b) — one instruction.
__device__ __forceinline__ uint32_t umed3(uint32_t a, uint32_t b, uint32_t c) {
  uint32_t d;
  asm("v_med3_u32 %0, %1, %2, %3" : "=v"(d) : "v"(a), "v"(b), "v"(c));
  return d;
}

// Packed f16 (VOP3P): 2 f16 lanes per instruction at full per-cycle rate.
__device__ __forceinline__ uint32_t pk_add_h(uint32_t a, uint32_t b) {
  uint32_t d;
  asm("v_pk_add_f16 %0, %1, %2" : "=v"(d) : "v"(a), "v"(b));
  return d;
}
__device__ __forceinline__ uint32_t pk_mul_h(uint32_t a, uint32_t b) {
  uint32_t d;
  asm("v_pk_mul_f16 %0, %1, %2" : "=v"(d) : "v"(a), "v"(b));
  return d;
}
__device__ __forceinline__ uint32_t pk_fma_h(uint32_t a, uint32_t b, uint32_t c) {
  uint32_t d;
  asm("v_pk_fma_f16 %0, %1, %2, %3" : "=v"(d) : "v"(a), "v"(b), "v"(c));
  return d;
}

// Insert key into ascending D-list, dropping the largest: 1 min + (D-1) med3.
template <int D>
__device__ __forceinline__ void insertD(uint32_t (&loc)[D], uint32_t key) {
  uint32_t prev = loc[0];
  loc[0] = u32min(prev, key);
#pragma unroll
  for (int m = 1; m < D; ++m) {
    const uint32_t cur = loc[m];
    loc[m] = umed3(prev, cur, key);
    prev = cur;
  }
}

// Dual-query f16-packed scan: one staged chunk feeds TWO query points per
// thread (groups 2g, 2g+1). Per t8 iteration (8 candidates x 2 queries =
// 16 evals): 3 uniform ds_read_b128 + two independent dist/insert chains.
// Key = (f16_d2_bits << 16) | j (monotone for d2>=0; ties -> ascending j;
// R7 measured absmax 0.0 with this key on this data). Self-distance exact 0
// (identical _Float16 conversions) -> rank-0 drop sound.
template <int DA, int DB>
__device__ __forceinline__ void scan_f16_dual(
    const _Float16* __restrict__ xh, const _Float16* __restrict__ yh,
    const _Float16* __restrict__ zh, int j0,
    uint32_t nax, uint32_t nay, uint32_t naz,
    uint32_t nbx, uint32_t nby, uint32_t nbz,
    uint32_t (&LA)[DA], uint32_t (&LB)[DB]) {
#pragma unroll
  for (int k = 0; k < DA; ++k) LA[k] = 0xFFFFFFFFu;
#pragma unroll
  for (int k = 0; k < DB; ++k) LB[k] = 0xFFFFFFFFu;
#pragma unroll 2
  for (int t8 = 0; t8 < CHN / 8; ++t8) {
    const uint4 xv = *(const uint4*)&xh[8 * t8];
    const uint4 yv = *(const uint4*)&yh[8 * t8];
    const uint4 zv = *(const uint4*)&zh[8 * t8];
    const uint32_t jb = (uint32_t)(j0 + 8 * t8);
#pragma unroll
    for (int p = 0; p < 4; ++p) {
      const uint32_t cx = (p == 0) ? xv.x : (p == 1) ? xv.y : (p == 2) ? xv.z : xv.w;
      const uint32_t cy = (p == 0) ? yv.x : (p == 1) ? yv.y : (p == 2) ? yv.z : yv.w;
      const uint32_t cz = (p == 0) ? zv.x : (p == 1) ? zv.y : (p == 2) ? zv.z : zv.w;
      const uint32_t je = jb + 2u * (uint32_t)p;
      {  // query A
        const uint32_t dx = pk_add_h(cx, nax);
        const uint32_t dy = pk_add_h(cy, nay);
        const uint32_t dz = pk_add_h(cz, naz);
        uint32_t d2 = pk_mul_h(dz, dz);
        d2 = pk_fma_h(dy, dy, d2);
        d2 = pk_fma_h(dx, dx, d2);
        insertD<DA>(LA, (d2 << 16) | je);
        insertD<DA>(LA, (d2 & 0xFFFF0000u) | (je + 1u));
      }
      {  // query B (independent chain — free ILP)
        const uint32_t dx = pk_add_h(cx, nbx);
        const uint32_t dy = pk_add_h(cy, nby);
        const uint32_t dz = pk_add_h(cz, nbz);
        uint32_t d2 = pk_mul_h(dz, dz);
        d2 = pk_fma_h(dy, dy, d2);
        d2 = pk_fma_h(dx, dx, d2);
        insertD<DB>(LB, (d2 << 16) | je);
        insertD<DB>(LB, (d2 & 0xFFFF0000u) | (je + 1u));
      }
    }
  }
}

// ---------------------------------------------------------------------------
// Kernel 1: per-(cloud,batch,point,chunk) top-3 by f16 key (top-4 with
// rank-0 self-drop for the self chunk — block-uniform). Change vs R7:
// TWO query groups (2g, 2g+1) share one staged chunk per block — grid
// 2048->1024 (still all-resident, 4 blocks/CU), LDS traffic and wave
// prologue/epilogue halved per evaluation, 2x independent chains per
// thread. Selection semantics and partial format unchanged.
// ---------------------------------------------------------------------------
__global__ void __launch_bounds__(256, 4)
knn_partial_k(const float* __restrict__ pred, const float* __restrict__ tgt,
              uint32_t* __restrict__ partial, uint32_t* __restrict__ ticket) {
  if (blockIdx.x == 0 && threadIdx.x == 0) *ticket = 0u;

  __shared__ __align__(16) _Float16 xh[CHN];
  __shared__ __align__(16) _Float16 yh[CHN];
  __shared__ __align__(16) _Float16 zh[CHN];

  int bx = blockIdx.x;
  const int chunk = bx & (NC - 1); bx >>= 4;
  const int g     = bx & 7;  bx >>= 3;   // query-group pair index (0..7)
  const int b     = bx & 3;  bx >>= 2;
  const int cloud = bx;  // 0 = pred, 1 = target

  const float* __restrict__ pts = (cloud ? tgt : pred) + (size_t)b * NPTS * 3;
  const int tid = threadIdx.x;
  const int ia = (2 * g) * 256 + tid;
  const int ib = (2 * g + 1) * 256 + tid;
  const int j0 = chunk * CHN;

  // Stage this chunk into f16 SoA LDS (one point per thread).
  {
    const int j = j0 + tid;
    xh[tid] = (_Float16)pts[3 * j + 0];
    yh[tid] = (_Float16)pts[3 * j + 1];
    zh[tid] = (_Float16)pts[3 * j + 2];
  }
  const float ax = pts[3 * ia + 0], ay = pts[3 * ia + 1], az = pts[3 * ia + 2];
  const float bxq = pts[3 * ib + 0], byq = pts[3 * ib + 1], bzq = pts[3 * ib + 2];
  __syncthreads();

  // Pre-negated packed query halves ({-q,-q}) -> plain pk_add in the loop.
  union HU { _Float16 h[2]; uint32_t u; };
  HU uax, uay, uaz, ubx, uby, ubz;
  uax.h[0] = uax.h[1] = -(_Float16)ax;
  uay.h[0] = uay.h[1] = -(_Float16)ay;
  uaz.h[0] = uaz.h[1] = -(_Float16)az;
  ubx.h[0] = ubx.h[1] = -(_Float16)bxq;
  uby.h[0] = uby.h[1] = -(_Float16)byq;
  ubz.h[0] = ubz.h[1] = -(_Float16)bzq;

  uint4 oa, ob;
  if (chunk == 2 * g) {            // query-A group is the self group
    uint32_t LA[SD + 1], LB[SD];
    scan_f16_dual<SD + 1, SD>(xh, yh, zh, j0, uax.u, uay.u, uaz.u,
                              ubx.u, uby.u, ubz.u, LA, LB);
    oa = make_uint4(LA[1], LA[2], LA[3], 0xFFFFFFFFu);
    ob = make_uint4(LB[0], LB[1], LB[2], 0xFFFFFFFFu);
  } else if (chunk == 2 * g + 1) { // query-B group is the self group
    uint32_t LA[SD], LB[SD + 1];
    scan_f16_dual<SD, SD + 1>(xh, yh, zh, j0, uax.u, uay.u, uaz.u,
                              ubx.u, uby.u, ubz.u, LA, LB);
    oa = make_uint4(LA[0], LA[1], LA[2], 0xFFFFFFFFu);
    ob = make_uint4(LB[1], LB[2], LB[3], 0xFFFFFFFFu);
  } else {
    uint32_t LA[SD], LB[SD];
    scan_f16_dual<SD, SD>(xh, yh, zh, j0, uax.u, uay.u, uaz.u,
                          ubx.u, uby.u, ubz.u, LA, LB);
    oa = make_uint4(LA[0], LA[1], LA[2], 0xFFFFFFFFu);
    ob = make_uint4(LB[0], LB[1], LB[2], 0xFFFFFFFFu);
  }
  const size_t base = (((size_t)(cloud * BATCH + b) * NC + chunk) * NPTS);
  *(uint4*)(partial + (base + (size_t)ia) * PD) = oa;
  *(uint4*)(partial + (base + (size_t)ib) * PD) = ob;
}

// Merge two sorted-ascending 8-lists, keep the smallest 8, sorted.
__device__ __forceinline__ void merge2(uint32_t A[KNN], const uint32_t B[KNN]) {
  uint32_t t[KNN];
#pragma unroll
  for (int m = 0; m < KNN; ++m) t[m] = u32min(A[m], B[KNN - 1 - m]);
#define CEU(x, y) { uint32_t lo = u32min(t[x], t[y]); uint32_t hi = u32max(t[x], t[y]); t[x] = lo; t[y] = hi; }
  CEU(0,4) CEU(1,5) CEU(2,6) CEU(3,7)
  CEU(0,2) CEU(1,3) CEU(4,6) CEU(5,7)
  CEU(0,1) CEU(2,3) CEU(4,5) CEU(6,7)
#undef CEU
#pragma unroll
  for (int m = 0; m < KNN; ++m) A[m] = t[m];
}

// Two sorted-4 lists -> one fully sorted 8 (bitonic cleanup, 12 CEs).
// Pad entries (0xFFFFFFFF) sort to the top and never reach the final top-8
// (16 chunks x 3 real keys = 48 >= 8 real candidates).
__device__ __forceinline__ void merge44(const uint2 a0, const uint2 a1,
                                        const uint2 b0, const uint2 b1,
                                        uint32_t s[KNN]) {
  s[0] = a0.x; s[1] = a0.y; s[2] = a1.x; s[3] = a1.y;
  s[4] = b1.y; s[5] = b1.x; s[6] = b0.y; s[7] = b0.x;  // b reversed -> bitonic
#define CEU(x, y) { uint32_t lo = u32min(s[x], s[y]); uint32_t hi = u32max(s[x], s[y]); s[x] = lo; s[y] = hi; }
  CEU(0,4) CEU(1,5) CEU(2,6) CEU(3,7)
  CEU(0,2) CEU(1,3) CEU(4,6) CEU(5,7)
  CEU(0,1) CEU(2,3) CEU(4,5) CEU(6,7)
#undef CEU
}

// Merge all NC=16 sorted-4 lists for point i -> global top-8 (sorted).
__device__ __forceinline__ void merge_all(const uint32_t* __restrict__ base,
                                          int i, uint32_t v[KNN]) {
  const size_t stride = (size_t)NPTS * PD;
  const uint32_t* p = base + (size_t)i * PD;
  uint2 q[NC][2];
#pragma unroll
  for (int c = 0; c < NC; ++c) {
    q[c][0] = *(const uint2*)(p + (size_t)c * stride);
    q[c][1] = *(const uint2*)(p + (size_t)c * stride + 2);
  }
  uint32_t L[NC / 2][KNN];
#pragma unroll
  for (int c = 0; c < NC / 2; ++c)
    merge44(q[2 * c][0], q[2 * c][1], q[2 * c + 1][0], q[2 * c + 1][1], L[c]);
  merge2(L[0], L[1]); merge2(L[2], L[3]); merge2(L[4], L[5]); merge2(L[6], L[7]);
  merge2(L[0], L[2]); merge2(L[4], L[6]);
  merge2(L[0], L[4]);
#pragma unroll
  for (int m = 0; m < KNN; ++m) v[m] = L[0][m];
}

// Per-cloud: coord gather (8 independent loads), density/cov/unit vectors.
// Indices live in the low 16 bits of the key (j < 4096 -> mask 0xFFF ok).
__device__ __forceinline__ void cloud_stats(const float* __restrict__ C, int i,
                                            const uint32_t v[KNN],
                                            float& dsum, float cov[6],
                                            float nx[KNN], float ny[KNN], float nz[KNN]) {
  const float qx = C[3 * i], qy = C[3 * i + 1], qz = C[3 * i + 2];
  float jx[KNN], jy[KNN], jz[KNN];
#pragma unroll
  for (int k = 0; k < KNN; ++k) {
    const int j = (int)(v[k] & 0xFFFu);
    jx[k] = C[3 * j]; jy[k] = C[3 * j + 1]; jz[k] = C[3 * j + 2];
  }
  dsum = 0.f;
#pragma unroll
  for (int m = 0; m < 6; ++m) cov[m] = 0.f;
#pragma unroll
  for (int k = 0; k < KNN; ++k) {
    const float ax = jx[k] - qx, ay = jy[k] - qy, az = jz[k] - qz;
    const float d2 = fmaf(ax, ax, fmaf(ay, ay, az * az));
    const float dist = sqrtf(fmaxf(d2, EPS_F));
    const float inv = 1.0f / fmaxf(dist, EPS_F);
    dsum += dist;
    cov[0] += ax * ax; cov[1] += ay * ay; cov[2] += az * az;
    cov[3] += ax * ay; cov[4] += ax * az; cov[5] += ay * az;
    nx[k] = ax * inv; ny[k] = ay * inv; nz[k] = az * inv;
  }
}

// ---------------------------------------------------------------------------
// Kernel 2 — proven verbatim: plain per-block stores + ticket finalize.
// ---------------------------------------------------------------------------
__global__ void __launch_bounds__(64, 1)
loss_k(const float* __restrict__ pred, const float* __restrict__ tgt,
       const uint32_t* __restrict__ partial, double* __restrict__ bsum,
       uint32_t* __restrict__ ticket, float* __restrict__ out) {
  const int p = blockIdx.x * 64 + threadIdx.x;   // 0 .. 16383
  const int b = p >> 12;
  const int i = p & (NPTS - 1);

  const float* __restrict__ P = pred + (size_t)b * NPTS * 3;
  const float* __restrict__ T = tgt  + (size_t)b * NPTS * 3;

  const size_t cstride = (size_t)NC * NPTS * PD;
  uint32_t vp[KNN], vt[KNN];
  merge_all(partial + (size_t)(0 * BATCH + b) * cstride, i, vp);
  merge_all(partial + (size_t)(1 * BATCH + b) * cstride, i, vt);

  float dsp, dst, pcov[6], tcov[6];
  float pnx[KNN], pny[KNN], pnz[KNN], tnx[KNN], tny[KNN], tnz[KNN];
  cloud_stats(P, i, vp, dsp, pcov, pnx, pny, pnz);
  cloud_stats(T, i, vt, dst, tcov, tnx, tny, tnz);

  float sdot = 0.f;
#pragma unroll
  for (int k = 0; k < KNN; ++k)
    sdot += pnx[k] * tnx[k] + pny[k] * tny[k] + pnz[k] * tnz[k];

  const float densp = dsp * (1.0f / KNN);
  const float denst = dst * (1.0f / KNN);
  float e = (densp - denst) * (densp - denst);

  const float dxx = (pcov[0] - tcov[0]) * (1.0f / KNN);
  const float dyy = (pcov[1] - tcov[1]) * (1.0f / KNN);
  const float dzz = (pcov[2] - tcov[2]) * (1.0f / KNN);
  const float dxy = (pcov[3] - tcov[3]) * (1.0f / KNN);
  const float dxz = (pcov[4] - tcov[4]) * (1.0f / KNN);
  const float dyz = (pcov[5] - tcov[5]) * (1.0f / KNN);
  float cfro = sqrtf(dxx * dxx + dyy * dyy + dzz * dzz
                     + 2.0f * (dxy * dxy + dxz * dxz + dyz * dyz));
  float s = sdot;

#pragma unroll
  for (int off = 32; off > 0; off >>= 1) {
    e    += __shfl_down(e, off);
    s    += __shfl_down(s, off);
    cfro += __shfl_down(cfro, off);
  }

  unsigned rank = 0u;
  if (threadIdx.x == 0) {
    double* d = bsum + 3 * (size_t)blockIdx.x;
    d[0] = (double)e; d[1] = (double)s; d[2] = (double)cfro;
    __threadfence();                       // release: stores visible device-wide
    rank = atomicAdd(ticket, 1u) + 1u;
  }
  rank = __shfl(rank, 0);
  if (rank == (unsigned)NBLK2) {           // last block: whole wave reduces
    __threadfence();                       // acquire
    double ee = 0.0, ss = 0.0, cc = 0.0;
#pragma unroll
    for (int g = 0; g < NBLK2 / 64; ++g) {
      double* d = bsum + 3 * (size_t)(threadIdx.x + 64 * g);
      ee += __hip_atomic_load(&d[0], __ATOMIC_RELAXED, __HIP_MEMORY_SCOPE_AGENT);
      ss += __hip_atomic_load(&d[1], __ATOMIC_RELAXED, __HIP_MEMORY_SCOPE_AGENT);
      cc += __hip_atomic_load(&d[2], __ATOMIC_RELAXED, __HIP_MEMORY_SCOPE_AGENT);
    }
#pragma unroll
    for (int off = 32; off > 0; off >>= 1) {
      ee += __shfl_down(ee, off);
      ss += __shfl_down(ss, off);
      cc += __shfl_down(cc, off);
    }
    if (threadIdx.x == 0) {
      const double BN = (double)BATCH * (double)NPTS;
      out[0] = (float)(ee / BN + 0.5 * (1.0 - ss / (BN * (double)KNN)) + 0.5 * (cc / BN));
    }
  }
}

extern "C" void kernel_launch(void* const* d_in, const int* in_sizes, int n_in,
                              void* d_out, int out_size, void* d_ws, size_t ws_size,
                              hipStream_t stream) {
  const float* pred = (const float*)d_in[0];
  const float* tgt  = (const float*)d_in[1];
  uint32_t* ticket  = (uint32_t*)((char*)d_ws + 64);     // 1 u32
  double*   bsum    = (double*)((char*)d_ws + 4096);     // 256 x 3 doubles (6 KB)
  uint32_t* partial = (uint32_t*)((char*)d_ws + 65536);  // 8.4 MB

  knn_partial_k<<<2 * BATCH * 8 * NC, 256, 0, stream>>>(
      pred, tgt, partial, ticket);
  loss_k<<<NBLK2, 64, 0, stream>>>(
      pred, tgt, partial, bsum, ticket, (float*)d_out);
}